// Round 5
// baseline (190.626 us; speedup 1.0000x reference)
//
#include <hip/hip_runtime.h>
#include <math.h>

#define N_NODES 100000
#define N_EDGES 1600000
#define NBUK 782                  // buckets of 128 nodes (dst >> 7); 782*128 = 100096
#define BNODES 128
#define CAPSH 12
#define CAP 4096                  // slots per bucket region (expected ~2046, 45 sigma margin)
#define NCHUNK 512                // scatter chunk blocks (2 blocks/CU co-resident)
#define CPE 3125                  // edges per chunk (512*3125 = 1.6M exact)
#define NTBLK 1563                // transform blocks in K1 (1563*1024 >= 1.6M node-feats)
#define WS 52                     // transposed-weight LDS stride (16B-aligned)
#define RPW (BNODES + 1)          // rowptr entries per bucket (129)

#define NTL(p) __builtin_nontemporal_load(p)

// ---------------------------------------------------------------------------
__device__ __forceinline__ unsigned bf16_rne(float x) {
    unsigned u = __float_as_uint(x);
    return (u + 0x7FFFu + ((u >> 16) & 1u)) >> 16;
}

// accumulate 4 packed (bf16,bf16) words with weight uu into registers
__device__ __forceinline__ void acc4(float* acc, uint4 w, float uu) {
    acc[0] += fmaf(uu, __uint_as_float(w.x & 0xFFFF0000u), __uint_as_float(w.x << 16));
    acc[1] += fmaf(uu, __uint_as_float(w.y & 0xFFFF0000u), __uint_as_float(w.y << 16));
    acc[2] += fmaf(uu, __uint_as_float(w.z & 0xFFFF0000u), __uint_as_float(w.z << 16));
    acc[3] += fmaf(uu, __uint_as_float(w.w & 0xFFFF0000u), __uint_as_float(w.w << 16));
}

// accumulate one edge (pk = src | u15<<17) from packed-bf16 Y table
__device__ __forceinline__ void edge_accum(unsigned pk,
                                           const uint4* __restrict__ YPH,
                                           float acc[16]) {
    float uu = (float)(pk >> 17) * (1.0f / 32767.0f);
    const uint4* yp = YPH + (size_t)(pk & 0x1FFFFu) * 4;
    uint4 w0 = yp[0], w1 = yp[1], w2 = yp[2], w3 = yp[3];
    acc4(acc + 0, w0, uu);
    acc4(acc + 4, w1, uu);
    acc4(acc + 8, w2, uu);
    acc4(acc + 12, w3, uu);
}

// two edges, loads grouped ahead of FMAs for memory-level parallelism
__device__ __forceinline__ void edge_accum2(unsigned p0, unsigned p1,
                                            const uint4* __restrict__ YPH,
                                            float acc[16]) {
    float u0 = (float)(p0 >> 17) * (1.0f / 32767.0f);
    float u1 = (float)(p1 >> 17) * (1.0f / 32767.0f);
    const uint4* a = YPH + (size_t)(p0 & 0x1FFFFu) * 4;
    const uint4* b = YPH + (size_t)(p1 & 0x1FFFFu) * 4;
    uint4 w0 = a[0], w1 = a[1], w2 = a[2], w3 = a[3];
    uint4 v0 = b[0], v1 = b[1], v2 = b[2], v3 = b[3];
    acc4(acc + 0, w0, u0);
    acc4(acc + 4, w1, u0);
    acc4(acc + 8, w2, u0);
    acc4(acc + 12, w3, u0);
    acc4(acc + 0, v0, u1);
    acc4(acc + 4, v1, u1);
    acc4(acc + 8, v2, u1);
    acc4(acc + 12, v3, u1);
}

// ---------------------------------------------------------------------------
// K1 (block = 1024): layer-1 transform (64 nodes/block); last block inits the
// per-bucket global cursors to b*CAP (consumed by K2 via device atomics).
__global__ __launch_bounds__(1024)
void transform1(const float* __restrict__ X,
                const float* __restrict__ W,
                const float* __restrict__ root,
                const float* __restrict__ bias,
                unsigned* __restrict__ YPH, float* __restrict__ R,
                int* __restrict__ cursor) {
    int t = threadIdx.x;
    if (blockIdx.x == NTBLK) {
        if (t < NBUK) cursor[t] = t * CAP;
        return;
    }
    __shared__ float sW0[16 * WS];
    __shared__ float sWd[16 * WS];
    __shared__ float sR[16 * WS];
    __shared__ float sB[16];
    for (int i = t; i < 48 * 16; i += 1024) {
        int f = i >> 4, o = i & 15;
        float w0 = W[i];
        float w1 = W[48 * 16 + i];
        sW0[o * WS + f] = w0;
        sWd[o * WS + f] = w1 - w0;
        sR[o * WS + f]  = root[i];
    }
    if (t < 16) sB[t] = bias[t];
    __syncthreads();

    int idx = blockIdx.x * 1024 + t;
    int n = idx >> 4;
    int o = idx & 15;
    if (n >= N_NODES) return;

    const float4* xr  = (const float4*)(X + (long)n * 48);
    const float4* w0p = (const float4*)(sW0 + o * WS);
    const float4* wdp = (const float4*)(sWd + o * WS);
    const float4* wrp = (const float4*)(sR  + o * WS);
    float a0 = 0.0f, a1 = 0.0f, ar = 0.0f;
#pragma unroll
    for (int fc = 0; fc < 12; ++fc) {
        float4 xv = xr[fc];
        float4 w0 = w0p[fc];
        float4 wd = wdp[fc];
        float4 wr = wrp[fc];
        a0 = fmaf(xv.x, w0.x, a0); a0 = fmaf(xv.y, w0.y, a0);
        a0 = fmaf(xv.z, w0.z, a0); a0 = fmaf(xv.w, w0.w, a0);
        a1 = fmaf(xv.x, wd.x, a1); a1 = fmaf(xv.y, wd.y, a1);
        a1 = fmaf(xv.z, wd.z, a1); a1 = fmaf(xv.w, wd.w, a1);
        ar = fmaf(xv.x, wr.x, ar); ar = fmaf(xv.y, wr.y, ar);
        ar = fmaf(xv.z, wr.z, ar); ar = fmaf(xv.w, wr.w, ar);
    }
    YPH[idx] = bf16_rne(a0) | (bf16_rne(a1) << 16);
    R[idx]   = ar + sB[o];
}

// ---------------------------------------------------------------------------
// K2 (block = 1024): per chunk, LDS counting sort by bucket (dst>>7); each
// chunk reserves its slice of each bucket's fixed CAP region with ONE global
// atomicAdd per bucket, then writes coalesced runs. ~54 KB LDS -> 2 blocks/CU.
__global__ __launch_bounds__(1024)
void scatter_edges(const int* __restrict__ src, const int* __restrict__ dst,
                   const float* __restrict__ u,
                   int* __restrict__ cursor,
                   unsigned* __restrict__ pkb, unsigned char* __restrict__ dlb) {
    __shared__ unsigned upk[CPE];        // unsorted pk
    __shared__ unsigned short ubuk[CPE]; // bucket per edge
    __shared__ unsigned char udl[CPE];   // unsorted dloc (0..127)
    __shared__ unsigned spk[CPE];        // sorted pk
    __shared__ unsigned char sdl[CPE];   // sorted dloc
    __shared__ unsigned short sbuk[CPE]; // sorted bucket
    __shared__ int lcur[NBUK];           // hist -> cursors
    __shared__ int gbase[NBUK];          // global_base[b] - local_excl[b]
    __shared__ int sc[1024];             // scan temp

    int t = threadIdx.x, c = blockIdx.x;

    for (int i = t; i < NBUK; i += 1024) lcur[i] = 0;
    __syncthreads();
    for (int j = t; j < CPE; j += 1024) {
        int e = c * CPE + j;
        int d = NTL(dst + e);
        float uu = NTL(u + e);
        uu = uu < 0.0f ? 0.0f : (uu > 1.0f ? 1.0f : uu);
        int u15 = (int)fmaf(uu, 32767.0f, 0.5f);
        upk[j] = (unsigned)NTL(src + e) | ((unsigned)u15 << 17);
        udl[j] = (unsigned char)(d & 127);
        int b = d >> 7;
        ubuk[j] = (unsigned short)b;
        atomicAdd(&lcur[b], 1);
    }
    __syncthreads();

    int v = (t < NBUK) ? lcur[t] : 0;
    sc[t] = v;
    __syncthreads();
    for (int off = 1; off < 1024; off <<= 1) {
        int x = (t >= off) ? sc[t - off] : 0;
        __syncthreads();
        sc[t] += x;
        __syncthreads();
    }
    if (t < NBUK) {
        int ex = sc[t] - v;          // exclusive local offset
        lcur[t] = ex;                // reuse as cursor
        int base = atomicAdd(&cursor[t], v);
        gbase[t] = base - ex;
    }
    __syncthreads();

    for (int j = t; j < CPE; j += 1024) {
        int b = ubuk[j];
        int p = atomicAdd(&lcur[b], 1);
        spk[p] = upk[j];
        sdl[p] = udl[j];
        sbuk[p] = (unsigned short)b;
    }
    __syncthreads();

    for (int j = t; j < CPE; j += 1024) {
        int b = sbuk[j];
        int g = gbase[b] + j;
        if (g < ((b + 1) << CAPSH)) {   // overflow guard (never expected)
            pkb[g] = spk[j];
            dlb[g] = sdl[j];
        }
    }
}

// ---------------------------------------------------------------------------
// K3 (block = 512, one block per 128-node bucket): LOCAL counting sort of the
// bucket's edges by node (LDS), write the sorted order back IN PLACE to pkb
// (this block is the region's sole reader/writer) + rowptr table for K4.
// Then per-node register accumulation (4 lanes/node, 2-round butterfly),
// ELU + layer-2 transform fused.
__global__ __launch_bounds__(512)
void aggregate1(const int* __restrict__ cursor,
                unsigned* __restrict__ pkb,
                const unsigned char* __restrict__ dlb,
                int* __restrict__ rptab,
                const uint4* __restrict__ YPH1,
                const float* __restrict__ R1,
                const float* __restrict__ W2,
                const float* __restrict__ root2,
                const float* __restrict__ b2,
                unsigned* __restrict__ YPH2,
                float* __restrict__ R2) {
    __shared__ unsigned spk[CAP];        // node-sorted pk (16 KB)
    __shared__ int rp[RPW];              // local rowptr
    __shared__ int cur[BNODES];          // hist, then scatter cursors
    __shared__ float sW0[256], sWd[256], sR[256], sB[16];
    int t = threadIdx.x, b = blockIdx.x;

    if (t < 256) {
        float w0 = W2[t], w1 = W2[256 + t];
        sW0[t] = w0;
        sWd[t] = w1 - w0;
        sR[t]  = root2[t];
    }
    if (t < 16) sB[t] = b2[t];
    if (t < BNODES) cur[t] = 0;
    __syncthreads();

    int cnt = cursor[b] - (b << CAPSH);
    if (cnt > CAP) cnt = CAP;
    unsigned* pk = pkb + ((size_t)b << CAPSH);
    const unsigned char* dl = dlb + ((size_t)b << CAPSH);
    int n4 = cnt >> 2, tail = cnt & 3, base4 = cnt & ~3;

    // pass 1: histogram by local node (4 dloc bytes per load)
    for (int j4 = t; j4 < n4; j4 += 512) {
        unsigned w = NTL((const unsigned*)dl + j4);
        atomicAdd(&cur[w & 255], 1);
        atomicAdd(&cur[(w >> 8) & 255], 1);
        atomicAdd(&cur[(w >> 16) & 255], 1);
        atomicAdd(&cur[w >> 24], 1);
    }
    if (t < tail) atomicAdd(&cur[NTL(dl + base4 + t)], 1);
    __syncthreads();

    // exclusive scan (128 entries, Hillis-Steele)
    int v = 0;
    if (t < BNODES) { v = cur[t]; rp[t] = v; }
    __syncthreads();
    for (int off = 1; off < BNODES; off <<= 1) {
        int x = 0;
        if (t < BNODES && t >= off) x = rp[t - off];
        __syncthreads();
        if (t < BNODES) rp[t] += x;
        __syncthreads();
    }
    if (t < BNODES) { int ex = rp[t] - v; rp[t] = ex; cur[t] = ex; }
    if (t == 0) rp[BNODES] = cnt;
    __syncthreads();

    // pass 2: scatter pk into node-sorted order (4 edges per iteration)
    for (int j4 = t; j4 < n4; j4 += 512) {
        uint4 p = ((const uint4*)pk)[j4];
        unsigned w = NTL((const unsigned*)dl + j4);
        spk[atomicAdd(&cur[w & 255], 1)]         = p.x;
        spk[atomicAdd(&cur[(w >> 8) & 255], 1)]  = p.y;
        spk[atomicAdd(&cur[(w >> 16) & 255], 1)] = p.z;
        spk[atomicAdd(&cur[w >> 24], 1)]         = p.w;
    }
    if (t < tail) {
        int j = base4 + t;
        spk[atomicAdd(&cur[NTL(dl + j)], 1)] = pk[j];
    }
    __syncthreads();

    // persist sorted order for K4: in-place pkb rewrite + rowptr table
    for (int j = t; j < cnt; j += 512) pk[j] = spk[j];
    if (t < RPW) rptab[b * RPW + t] = rp[t];

    // per-node register accumulation: 4 lanes per node
    int node = t >> 2, q = t & 3;
    int n = (b << 7) + node;
    int beg = rp[node], end = rp[node + 1];
    int deg = end - beg;

    float acc[16];
#pragma unroll
    for (int i = 0; i < 16; ++i) acc[i] = 0.0f;
    int j = beg + q;
    for (; j + 4 < end; j += 8)
        edge_accum2(spk[j], spk[j + 4], YPH1, acc);
    if (j < end) edge_accum(spk[j], YPH1, acc);

#pragma unroll
    for (int mask = 1; mask <= 2; mask <<= 1) {
#pragma unroll
        for (int i = 0; i < 16; ++i) acc[i] += __shfl_xor(acc[i], mask);
    }

    if (n < N_NODES) {
        float inv = 1.0f / (deg > 0 ? (float)deg : 1.0f);
        // full H row (ELU'd) in registers
        float h16[16];
        const float4* rrp = (const float4*)(R1 + (size_t)n * 16);
#pragma unroll
        for (int qq = 0; qq < 4; ++qq) {
            float4 rr = rrp[qq];
            float w;
            w = fmaf(acc[4 * qq + 0], inv, rr.x); h16[4 * qq + 0] = w > 0.0f ? w : expm1f(w);
            w = fmaf(acc[4 * qq + 1], inv, rr.y); h16[4 * qq + 1] = w > 0.0f ? w : expm1f(w);
            w = fmaf(acc[4 * qq + 2], inv, rr.z); h16[4 * qq + 2] = w > 0.0f ? w : expm1f(w);
            w = fmaf(acc[4 * qq + 3], inv, rr.w); h16[4 * qq + 3] = w > 0.0f ? w : expm1f(w);
        }

        // layer-2 transform: this lane computes 4 outputs o = 4q .. 4q+3
        float a0[4] = {0, 0, 0, 0}, a1[4] = {0, 0, 0, 0}, ar[4] = {0, 0, 0, 0};
        int o0 = q * 4;
#pragma unroll
        for (int f = 0; f < 16; ++f) {
            float hv = h16[f];
#pragma unroll
            for (int o = 0; o < 4; ++o) {
                a0[o] = fmaf(hv, sW0[f * 16 + o0 + o], a0[o]);
                a1[o] = fmaf(hv, sWd[f * 16 + o0 + o], a1[o]);
                ar[o] = fmaf(hv, sR [f * 16 + o0 + o], ar[o]);
            }
        }
        uint4 yw;
        yw.x = bf16_rne(a0[0]) | (bf16_rne(a1[0]) << 16);
        yw.y = bf16_rne(a0[1]) | (bf16_rne(a1[1]) << 16);
        yw.z = bf16_rne(a0[2]) | (bf16_rne(a1[2]) << 16);
        yw.w = bf16_rne(a0[3]) | (bf16_rne(a1[3]) << 16);
        ((uint4*)YPH2)[(size_t)n * 4 + q] = yw;
        float4 rv;
        rv.x = ar[0] + sB[o0 + 0];
        rv.y = ar[1] + sB[o0 + 1];
        rv.z = ar[2] + sB[o0 + 2];
        rv.w = ar[3] + sB[o0 + 3];
        ((float4*)R2)[(size_t)n * 4 + q] = rv;
    }
}

// ---------------------------------------------------------------------------
// K4 (block = 512, one block per bucket): NO sort — reads the node-sorted pkb
// + rowptr produced by K3. Tiny LDS -> 4 blocks/CU. Register accumulation,
// then log-softmax across the node's 4 lanes.
__global__ __launch_bounds__(512)
void aggregate2(const int* __restrict__ rptab,
                const unsigned* __restrict__ pkb,
                const uint4* __restrict__ YPH2,
                const float* __restrict__ R2,
                float* __restrict__ out) {
    __shared__ int rp[RPW];
    int t = threadIdx.x, b = blockIdx.x;

    if (t < RPW) rp[t] = rptab[b * RPW + t];
    __syncthreads();

    const unsigned* pk = pkb + ((size_t)b << CAPSH);
    int node = t >> 2, q = t & 3;
    int n = (b << 7) + node;
    int beg = rp[node], end = rp[node + 1];
    int deg = end - beg;

    float acc[16];
#pragma unroll
    for (int i = 0; i < 16; ++i) acc[i] = 0.0f;
    int j = beg + q;
    for (; j + 4 < end; j += 8)
        edge_accum2(NTL(pk + j), NTL(pk + j + 4), YPH2, acc);
    if (j < end) edge_accum(NTL(pk + j), YPH2, acc);

#pragma unroll
    for (int mask = 1; mask <= 2; mask <<= 1) {
#pragma unroll
        for (int i = 0; i < 16; ++i) acc[i] += __shfl_xor(acc[i], mask);
    }

    if (n < N_NODES) {
        float inv = 1.0f / (deg > 0 ? (float)deg : 1.0f);
        float4 rr = ((const float4*)R2)[(size_t)n * 4 + q];
        float v0 = fmaf(acc[4 * q + 0], inv, rr.x);
        float v1 = fmaf(acc[4 * q + 1], inv, rr.y);
        float v2 = fmaf(acc[4 * q + 2], inv, rr.z);
        float v3 = fmaf(acc[4 * q + 3], inv, rr.w);
        float m = fmaxf(fmaxf(v0, v1), fmaxf(v2, v3));
        m = fmaxf(m, __shfl_xor(m, 1));
        m = fmaxf(m, __shfl_xor(m, 2));
        float s = expf(v0 - m) + expf(v1 - m) + expf(v2 - m) + expf(v3 - m);
        s += __shfl_xor(s, 1);
        s += __shfl_xor(s, 2);
        float lse = m + logf(s);
        float4 ov = make_float4(v0 - lse, v1 - lse, v2 - lse, v3 - lse);
        ((float4*)out)[(size_t)n * 4 + q] = ov;
    }
}

// ---------------------------------------------------------------------------
extern "C" void kernel_launch(void* const* d_in, const int* in_sizes, int n_in,
                              void* d_out, int out_size, void* d_ws, size_t ws_size,
                              hipStream_t stream) {
    const float* x         = (const float*)d_in[0];
    const float* edge_attr = (const float*)d_in[1];
    const int*   edge_idx  = (const int*)d_in[2];
    const float* W1        = (const float*)d_in[3];
    const float* root1     = (const float*)d_in[4];
    const float* b1        = (const float*)d_in[5];
    const float* W2        = (const float*)d_in[6];
    const float* root2     = (const float*)d_in[7];
    const float* b2        = (const float*)d_in[8];
    float* out = (float*)d_out;

    const int* src = edge_idx;
    const int* dst = edge_idx + N_EDGES;

    // workspace layout (byte offsets, 16B aligned), total ~42.0 MB
    char* ws = (char*)d_ws;
    unsigned*      pkb    = (unsigned*)(ws);                  // 782*4096*4 = 12,812,288
    unsigned char* dlb    = (unsigned char*)(ws + 12812288);  // 782*4096   =  3,203,072
    unsigned*      YPH1   = (unsigned*)(ws + 16015360);       //  6,400,000
    float*         R1     = (float*)(ws + 22415360);          //  6,400,000
    unsigned*      YPH2   = (unsigned*)(ws + 28815360);       //  6,400,000
    float*         R2     = (float*)(ws + 35215360);          //  6,400,000
    int*           cursor = (int*)(ws + 41615360);            //      3,128
    int*           rptab  = (int*)(ws + 41618496);            //    403,512

    transform1<<<dim3(NTBLK + 1), 1024, 0, stream>>>(
        x, W1, root1, b1, YPH1, R1, cursor);

    scatter_edges<<<dim3(NCHUNK), 1024, 0, stream>>>(
        src, dst, edge_attr, cursor, pkb, dlb);

    aggregate1<<<dim3(NBUK), 512, 0, stream>>>(
        cursor, pkb, dlb, rptab, (const uint4*)YPH1, R1, W2, root2, b2, YPH2, R2);

    aggregate2<<<dim3(NBUK), 512, 0, stream>>>(
        rptab, pkb, (const uint4*)YPH2, R2, out);
}

// Round 6
// 179.729 us; speedup vs baseline: 1.0606x; 1.0606x over previous
//
#include <hip/hip_runtime.h>
#include <math.h>

#define N_NODES 100000
#define N_EDGES 1600000
#define NBUK 782                  // buckets of 128 nodes (dst >> 7); 782*128 = 100096
#define BNODES 128
#define CAPSH 12
#define CAP 4096                  // slots per bucket region (expected ~2046)
#define NCHUNK 512                // scatter chunk blocks
#define CPE 3125                  // edges per chunk (512*3125 = 1.6M exact)
#define NTBLK 1563                // transform blocks (1563*1024 >= 1.6M node-feats)
#define WS 52                     // transposed-weight LDS stride (16B-aligned)
#define RPW (BNODES + 1)          // rowptr entries per bucket (129)

// dynamic-LDS layout for the merged kernel's scatter path (54,144 B total)
#define SM_LCUR   0               // int[NBUK]        3128
#define SM_GBASE  3128            // int[NBUK]        3128
#define SM_SC     6256            // int[1024]        4096
#define SM_UPK    10352           // uint[CPE]       12500
#define SM_SPK    22852           // uint[CPE]       12500
#define SM_UBUK   35352           // ushort[CPE]      6250
#define SM_SBUK   41602           // ushort[CPE]      6250
#define SM_UDL    47852           // uchar[CPE]       3125
#define SM_SDL    50977           // uchar[CPE]       3125
#define SM_TOTAL  54144

#define NTL(p) __builtin_nontemporal_load(p)

// ---------------------------------------------------------------------------
__device__ __forceinline__ unsigned bf16_rne(float x) {
    unsigned u = __float_as_uint(x);
    return (u + 0x7FFFu + ((u >> 16) & 1u)) >> 16;
}

// accumulate one 16B chunk (4 packed bf16 pairs) with weight uu
__device__ __forceinline__ void accq(float acc[4], uint4 w, float uu) {
    acc[0] += fmaf(uu, __uint_as_float(w.x & 0xFFFF0000u), __uint_as_float(w.x << 16));
    acc[1] += fmaf(uu, __uint_as_float(w.y & 0xFFFF0000u), __uint_as_float(w.y << 16));
    acc[2] += fmaf(uu, __uint_as_float(w.z & 0xFFFF0000u), __uint_as_float(w.z << 16));
    acc[3] += fmaf(uu, __uint_as_float(w.w & 0xFFFF0000u), __uint_as_float(w.w << 16));
}

// ---------------------------------------------------------------------------
// K1 merged (block = 1024): blocks [0,NCHUNK) bucket-scatter the edges;
// blocks [NCHUNK, NCHUNK+NTBLK) run the layer-1 transform. The two halves are
// data-independent and overlap on the device. cursor[] is pre-zeroed by a
// hipMemsetAsync; the b*CAP region base is added at use.
__global__ __launch_bounds__(1024)
void fused_transform_scatter(const float* __restrict__ X,
                             const float* __restrict__ W,
                             const float* __restrict__ root,
                             const float* __restrict__ bias,
                             unsigned* __restrict__ YPH, float* __restrict__ R,
                             const int* __restrict__ src,
                             const int* __restrict__ dst,
                             const float* __restrict__ u,
                             int* __restrict__ cursor,
                             unsigned* __restrict__ pkb,
                             unsigned char* __restrict__ dlb) {
    extern __shared__ char smem[];
    int t = threadIdx.x;
    if (blockIdx.x < NCHUNK) {
        // ------------------------------------------------ scatter path
        int c = blockIdx.x;
        int* lcur            = (int*)(smem + SM_LCUR);
        int* gbase           = (int*)(smem + SM_GBASE);
        int* sc              = (int*)(smem + SM_SC);
        unsigned* upk        = (unsigned*)(smem + SM_UPK);
        unsigned* spk        = (unsigned*)(smem + SM_SPK);
        unsigned short* ubuk = (unsigned short*)(smem + SM_UBUK);
        unsigned short* sbuk = (unsigned short*)(smem + SM_SBUK);
        unsigned char* udl   = (unsigned char*)(smem + SM_UDL);
        unsigned char* sdl   = (unsigned char*)(smem + SM_SDL);

        for (int i = t; i < NBUK; i += 1024) lcur[i] = 0;
        __syncthreads();
        for (int j = t; j < CPE; j += 1024) {
            int e = c * CPE + j;
            int d = NTL(dst + e);
            float uu = NTL(u + e);
            uu = uu < 0.0f ? 0.0f : (uu > 1.0f ? 1.0f : uu);
            int u15 = (int)fmaf(uu, 32767.0f, 0.5f);
            upk[j] = (unsigned)NTL(src + e) | ((unsigned)u15 << 17);
            udl[j] = (unsigned char)(d & 127);
            int b = d >> 7;
            ubuk[j] = (unsigned short)b;
            atomicAdd(&lcur[b], 1);
        }
        __syncthreads();

        int v = (t < NBUK) ? lcur[t] : 0;
        sc[t] = v;
        __syncthreads();
        for (int off = 1; off < 1024; off <<= 1) {
            int x = (t >= off) ? sc[t - off] : 0;
            __syncthreads();
            sc[t] += x;
            __syncthreads();
        }
        if (t < NBUK) {
            int ex = sc[t] - v;          // exclusive local offset
            lcur[t] = ex;                // reuse as cursor
            int base = (t << CAPSH) + atomicAdd(&cursor[t], v);
            gbase[t] = base - ex;
        }
        __syncthreads();

        for (int j = t; j < CPE; j += 1024) {
            int b = ubuk[j];
            int p = atomicAdd(&lcur[b], 1);
            spk[p] = upk[j];
            sdl[p] = udl[j];
            sbuk[p] = (unsigned short)b;
        }
        __syncthreads();

        for (int j = t; j < CPE; j += 1024) {
            int b = sbuk[j];
            int g = gbase[b] + j;
            if (g < ((b + 1) << CAPSH)) {   // overflow guard (never expected)
                pkb[g] = spk[j];
                dlb[g] = sdl[j];
            }
        }
    } else {
        // ------------------------------------------------ transform path
        float* sW0 = (float*)smem;
        float* sWd = (float*)(smem + 3328);
        float* sR  = (float*)(smem + 6656);
        float* sB  = (float*)(smem + 9984);
        int bid = blockIdx.x - NCHUNK;
        for (int i = t; i < 48 * 16; i += 1024) {
            int f = i >> 4, o = i & 15;
            float w0 = W[i];
            float w1 = W[48 * 16 + i];
            sW0[o * WS + f] = w0;
            sWd[o * WS + f] = w1 - w0;
            sR[o * WS + f]  = root[i];
        }
        if (t < 16) sB[t] = bias[t];
        __syncthreads();

        int idx = bid * 1024 + t;
        int n = idx >> 4;
        int o = idx & 15;
        if (n >= N_NODES) return;

        const float4* xr  = (const float4*)(X + (long)n * 48);
        const float4* w0p = (const float4*)(sW0 + o * WS);
        const float4* wdp = (const float4*)(sWd + o * WS);
        const float4* wrp = (const float4*)(sR  + o * WS);
        float a0 = 0.0f, a1 = 0.0f, ar = 0.0f;
#pragma unroll
        for (int fc = 0; fc < 12; ++fc) {
            float4 xv = xr[fc];
            float4 w0 = w0p[fc];
            float4 wd = wdp[fc];
            float4 wr = wrp[fc];
            a0 = fmaf(xv.x, w0.x, a0); a0 = fmaf(xv.y, w0.y, a0);
            a0 = fmaf(xv.z, w0.z, a0); a0 = fmaf(xv.w, w0.w, a0);
            a1 = fmaf(xv.x, wd.x, a1); a1 = fmaf(xv.y, wd.y, a1);
            a1 = fmaf(xv.z, wd.z, a1); a1 = fmaf(xv.w, wd.w, a1);
            ar = fmaf(xv.x, wr.x, ar); ar = fmaf(xv.y, wr.y, ar);
            ar = fmaf(xv.z, wr.z, ar); ar = fmaf(xv.w, wr.w, ar);
        }
        YPH[idx] = bf16_rne(a0) | (bf16_rne(a1) << 16);
        R[idx]   = ar + sB[o];
    }
}

// ---------------------------------------------------------------------------
// K3 (block = 512, one block per 128-node bucket): LOCAL counting sort by
// node in LDS (persisted to pkb + rptab for K4), then QUAD-SPLIT register
// aggregation: the node's 4 lanes each read one 16B quarter of every edge's
// Y-row (consecutive addresses -> one 64B segment per quad per edge; 4x fewer
// cache-line touches per wave-load than row-per-lane). ELU + layer-2 fused.
__global__ __launch_bounds__(512)
void aggregate1(const int* __restrict__ cursor,
                unsigned* __restrict__ pkb,
                const unsigned char* __restrict__ dlb,
                int* __restrict__ rptab,
                const uint4* __restrict__ YPH1,
                const float* __restrict__ R1,
                const float* __restrict__ W2,
                const float* __restrict__ root2,
                const float* __restrict__ b2,
                unsigned* __restrict__ YPH2,
                float* __restrict__ R2) {
    __shared__ unsigned spk[CAP];        // node-sorted pk (16 KB)
    __shared__ int rp[RPW];              // local rowptr
    __shared__ int cur[BNODES];          // hist, then scatter cursors
    __shared__ float sW0[256], sWd[256], sR[256], sB[16];
    int t = threadIdx.x, b = blockIdx.x;

    if (t < 256) {
        float w0 = W2[t], w1 = W2[256 + t];
        sW0[t] = w0;
        sWd[t] = w1 - w0;
        sR[t]  = root2[t];
    }
    if (t < 16) sB[t] = b2[t];
    if (t < BNODES) cur[t] = 0;
    __syncthreads();

    int cnt = cursor[b];
    if (cnt > CAP) cnt = CAP;
    unsigned* pk = pkb + ((size_t)b << CAPSH);
    const unsigned char* dl = dlb + ((size_t)b << CAPSH);
    int n4 = cnt >> 2, tail = cnt & 3, base4 = cnt & ~3;

    // pass 1: histogram by local node (4 dloc bytes per load)
    for (int j4 = t; j4 < n4; j4 += 512) {
        unsigned w = NTL((const unsigned*)dl + j4);
        atomicAdd(&cur[w & 255], 1);
        atomicAdd(&cur[(w >> 8) & 255], 1);
        atomicAdd(&cur[(w >> 16) & 255], 1);
        atomicAdd(&cur[w >> 24], 1);
    }
    if (t < tail) atomicAdd(&cur[NTL(dl + base4 + t)], 1);
    __syncthreads();

    // exclusive scan (128 entries, Hillis-Steele)
    int v = 0;
    if (t < BNODES) { v = cur[t]; rp[t] = v; }
    __syncthreads();
    for (int off = 1; off < BNODES; off <<= 1) {
        int x = 0;
        if (t < BNODES && t >= off) x = rp[t - off];
        __syncthreads();
        if (t < BNODES) rp[t] += x;
        __syncthreads();
    }
    if (t < BNODES) { int ex = rp[t] - v; rp[t] = ex; cur[t] = ex; }
    if (t == 0) rp[BNODES] = cnt;
    __syncthreads();

    // pass 2: scatter pk into node-sorted order (4 edges per iteration)
    for (int j4 = t; j4 < n4; j4 += 512) {
        uint4 p = ((const uint4*)pk)[j4];
        unsigned w = NTL((const unsigned*)dl + j4);
        spk[atomicAdd(&cur[w & 255], 1)]         = p.x;
        spk[atomicAdd(&cur[(w >> 8) & 255], 1)]  = p.y;
        spk[atomicAdd(&cur[(w >> 16) & 255], 1)] = p.z;
        spk[atomicAdd(&cur[w >> 24], 1)]         = p.w;
    }
    if (t < tail) {
        int j = base4 + t;
        spk[atomicAdd(&cur[NTL(dl + j)], 1)] = pk[j];
    }
    __syncthreads();

    // persist sorted order for K4: in-place pkb rewrite + rowptr table
    for (int j = t; j < cnt; j += 512) pk[j] = spk[j];
    if (t < RPW) rptab[b * RPW + t] = rp[t];

    // quad-split aggregation: 4 lanes per node, lane q owns features 4q..4q+3
    int node = t >> 2, q = t & 3;
    int n = (b << 7) + node;
    int beg = rp[node], end = rp[node + 1];
    int deg = end - beg;
    const float C = 1.0f / 32767.0f;

    float acc[4] = {0.0f, 0.0f, 0.0f, 0.0f};
    int j = beg;
    for (; j + 3 < end; j += 4) {
        unsigned p0 = spk[j], p1 = spk[j + 1], p2 = spk[j + 2], p3 = spk[j + 3];
        uint4 w0 = YPH1[(size_t)(p0 & 0x1FFFFu) * 4 + q];
        uint4 w1 = YPH1[(size_t)(p1 & 0x1FFFFu) * 4 + q];
        uint4 w2 = YPH1[(size_t)(p2 & 0x1FFFFu) * 4 + q];
        uint4 w3 = YPH1[(size_t)(p3 & 0x1FFFFu) * 4 + q];
        accq(acc, w0, (float)(p0 >> 17) * C);
        accq(acc, w1, (float)(p1 >> 17) * C);
        accq(acc, w2, (float)(p2 >> 17) * C);
        accq(acc, w3, (float)(p3 >> 17) * C);
    }
    for (; j < end; ++j) {
        unsigned p = spk[j];
        uint4 w = YPH1[(size_t)(p & 0x1FFFFu) * 4 + q];
        accq(acc, w, (float)(p >> 17) * C);
    }

    if (n < N_NODES) {
        float inv = 1.0f / (deg > 0 ? (float)deg : 1.0f);
        float4 rr = ((const float4*)(R1 + (size_t)n * 16))[q];
        float hq[4], w;
        w = fmaf(acc[0], inv, rr.x); hq[0] = w > 0.0f ? w : expm1f(w);
        w = fmaf(acc[1], inv, rr.y); hq[1] = w > 0.0f ? w : expm1f(w);
        w = fmaf(acc[2], inv, rr.z); hq[2] = w > 0.0f ? w : expm1f(w);
        w = fmaf(acc[3], inv, rr.w); hq[3] = w > 0.0f ? w : expm1f(w);

        // reconstruct the full h row from the quad (16 shuffles)
        int qbase = (t & 63) & ~3;
        float h16[16];
#pragma unroll
        for (int p = 0; p < 4; ++p) {
            h16[4 * p + 0] = __shfl(hq[0], qbase + p);
            h16[4 * p + 1] = __shfl(hq[1], qbase + p);
            h16[4 * p + 2] = __shfl(hq[2], qbase + p);
            h16[4 * p + 3] = __shfl(hq[3], qbase + p);
        }

        // layer-2 transform: this lane computes 4 outputs o = 4q .. 4q+3
        float a0[4] = {0, 0, 0, 0}, a1[4] = {0, 0, 0, 0}, ar[4] = {0, 0, 0, 0};
        int o0 = q * 4;
#pragma unroll
        for (int f = 0; f < 16; ++f) {
            float hv = h16[f];
#pragma unroll
            for (int o = 0; o < 4; ++o) {
                a0[o] = fmaf(hv, sW0[f * 16 + o0 + o], a0[o]);
                a1[o] = fmaf(hv, sWd[f * 16 + o0 + o], a1[o]);
                ar[o] = fmaf(hv, sR [f * 16 + o0 + o], ar[o]);
            }
        }
        uint4 yw;
        yw.x = bf16_rne(a0[0]) | (bf16_rne(a1[0]) << 16);
        yw.y = bf16_rne(a0[1]) | (bf16_rne(a1[1]) << 16);
        yw.z = bf16_rne(a0[2]) | (bf16_rne(a1[2]) << 16);
        yw.w = bf16_rne(a0[3]) | (bf16_rne(a1[3]) << 16);
        ((uint4*)YPH2)[(size_t)n * 4 + q] = yw;
        float4 rv;
        rv.x = ar[0] + sB[o0 + 0];
        rv.y = ar[1] + sB[o0 + 1];
        rv.z = ar[2] + sB[o0 + 2];
        rv.w = ar[3] + sB[o0 + 3];
        ((float4*)R2)[(size_t)n * 4 + q] = rv;
    }
}

// ---------------------------------------------------------------------------
// K4 (block = 512, one block per bucket): reads node-sorted pkb + rptab from
// K3; quad-split gather (lane q owns output features 4q..4q+3 directly — no
// butterfly), then log-softmax across the node's 4 lanes.
__global__ __launch_bounds__(512)
void aggregate2(const int* __restrict__ rptab,
                const unsigned* __restrict__ pkb,
                const uint4* __restrict__ YPH2,
                const float* __restrict__ R2,
                float* __restrict__ out) {
    __shared__ int rp[RPW];
    int t = threadIdx.x, b = blockIdx.x;

    if (t < RPW) rp[t] = rptab[b * RPW + t];
    __syncthreads();

    const unsigned* pk = pkb + ((size_t)b << CAPSH);
    int node = t >> 2, q = t & 3;
    int n = (b << 7) + node;
    int beg = rp[node], end = rp[node + 1];
    int deg = end - beg;
    const float C = 1.0f / 32767.0f;

    float acc[4] = {0.0f, 0.0f, 0.0f, 0.0f};
    int j = beg;
    for (; j + 3 < end; j += 4) {
        unsigned p0 = pk[j], p1 = pk[j + 1], p2 = pk[j + 2], p3 = pk[j + 3];
        uint4 w0 = YPH2[(size_t)(p0 & 0x1FFFFu) * 4 + q];
        uint4 w1 = YPH2[(size_t)(p1 & 0x1FFFFu) * 4 + q];
        uint4 w2 = YPH2[(size_t)(p2 & 0x1FFFFu) * 4 + q];
        uint4 w3 = YPH2[(size_t)(p3 & 0x1FFFFu) * 4 + q];
        accq(acc, w0, (float)(p0 >> 17) * C);
        accq(acc, w1, (float)(p1 >> 17) * C);
        accq(acc, w2, (float)(p2 >> 17) * C);
        accq(acc, w3, (float)(p3 >> 17) * C);
    }
    for (; j < end; ++j) {
        unsigned p = pk[j];
        uint4 w = YPH2[(size_t)(p & 0x1FFFFu) * 4 + q];
        accq(acc, w, (float)(p >> 17) * C);
    }

    if (n < N_NODES) {
        float inv = 1.0f / (deg > 0 ? (float)deg : 1.0f);
        float4 rr = ((const float4*)R2)[(size_t)n * 4 + q];
        float v0 = fmaf(acc[0], inv, rr.x);
        float v1 = fmaf(acc[1], inv, rr.y);
        float v2 = fmaf(acc[2], inv, rr.z);
        float v3 = fmaf(acc[3], inv, rr.w);
        float m = fmaxf(fmaxf(v0, v1), fmaxf(v2, v3));
        m = fmaxf(m, __shfl_xor(m, 1));
        m = fmaxf(m, __shfl_xor(m, 2));
        float s = expf(v0 - m) + expf(v1 - m) + expf(v2 - m) + expf(v3 - m);
        s += __shfl_xor(s, 1);
        s += __shfl_xor(s, 2);
        float lse = m + logf(s);
        float4 ov = make_float4(v0 - lse, v1 - lse, v2 - lse, v3 - lse);
        ((float4*)out)[(size_t)n * 4 + q] = ov;
    }
}

// ---------------------------------------------------------------------------
extern "C" void kernel_launch(void* const* d_in, const int* in_sizes, int n_in,
                              void* d_out, int out_size, void* d_ws, size_t ws_size,
                              hipStream_t stream) {
    const float* x         = (const float*)d_in[0];
    const float* edge_attr = (const float*)d_in[1];
    const int*   edge_idx  = (const int*)d_in[2];
    const float* W1        = (const float*)d_in[3];
    const float* root1     = (const float*)d_in[4];
    const float* b1        = (const float*)d_in[5];
    const float* W2        = (const float*)d_in[6];
    const float* root2     = (const float*)d_in[7];
    const float* b2        = (const float*)d_in[8];
    float* out = (float*)d_out;

    const int* src = edge_idx;
    const int* dst = edge_idx + N_EDGES;

    // workspace layout (byte offsets, 16B aligned), total ~42.0 MB
    char* ws = (char*)d_ws;
    unsigned*      pkb    = (unsigned*)(ws);                  // 782*4096*4 = 12,812,288
    unsigned char* dlb    = (unsigned char*)(ws + 12812288);  // 782*4096   =  3,203,072
    unsigned*      YPH1   = (unsigned*)(ws + 16015360);       //  6,400,000
    float*         R1     = (float*)(ws + 22415360);          //  6,400,000
    unsigned*      YPH2   = (unsigned*)(ws + 28815360);       //  6,400,000
    float*         R2     = (float*)(ws + 35215360);          //  6,400,000
    int*           cursor = (int*)(ws + 41615360);            //      3,128
    int*           rptab  = (int*)(ws + 41618496);            //    403,512

    hipMemsetAsync(cursor, 0, NBUK * sizeof(int), stream);

    fused_transform_scatter<<<dim3(NCHUNK + NTBLK), 1024, SM_TOTAL, stream>>>(
        x, W1, root1, b1, YPH1, R1, src, dst, edge_attr, cursor, pkb, dlb);

    aggregate1<<<dim3(NBUK), 512, 0, stream>>>(
        cursor, pkb, dlb, rptab, (const uint4*)YPH1, R1, W2, root2, b2, YPH2, R2);

    aggregate2<<<dim3(NBUK), 512, 0, stream>>>(
        rptab, pkb, (const uint4*)YPH2, R2, out);
}